// Round 4
// baseline (2618.179 us; speedup 1.0000x reference)
//
#include <hip/hip_runtime.h>
#include <hip/hip_bf16.h>
#include <cstdint>
#include <cstddef>

#define DEV __device__ __forceinline__

typedef __attribute__((ext_vector_type(8))) short short8;   // 8 bf16 (4 VGPR)
typedef __attribute__((ext_vector_type(4))) float f32x4;
typedef unsigned short u16;
typedef unsigned int u32;

static constexpr int Vv = 50257;
static constexpr int Dd = 768;
static constexpr int Ll = 12;
static constexpr int Hh = 12;
static constexpr int Ff = 3072;
static constexpr int Ss = 1024;
static constexpr int Bbatch = 2;
static constexpr int DHh = 64;
static constexpr int Mtok = Bbatch * Ss;   // 2048
static constexpr int NQKV = 3 * Dd;        // 2304
static constexpr int VPAD = 50304;         // 50257 padded to 128-multiple

DEV u16 f2bf(float f){ u32 x; __builtin_memcpy(&x, &f, 4); x += 0x7fffu + ((x >> 16) & 1u); return (u16)(x >> 16); }

DEV void gld_lds16(const void* g, void* l){
  __builtin_amdgcn_global_load_lds((const __attribute__((address_space(1))) void*)g,
                                   (__attribute__((address_space(3))) void*)l, 16, 0, 0);
}

template<int N> DEV void waitv(){
  if constexpr (N == 0) asm volatile("s_waitcnt vmcnt(0)" ::: "memory");
  else if constexpr (N == 2) asm volatile("s_waitcnt vmcnt(2)" ::: "memory");
  else if constexpr (N == 3) asm volatile("s_waitcnt vmcnt(3)" ::: "memory");
  else if constexpr (N == 4) asm volatile("s_waitcnt vmcnt(4)" ::: "memory");
}

// ---------------- embedding ----------------
__global__ void k_embed(const int* __restrict__ ids, const float* __restrict__ tok,
                        const float* __restrict__ pos, float* __restrict__ x){
  int t = blockIdx.x;
  int id = ids[t];
  int s = t & (Ss - 1);
  const float* tr = tok + (size_t)id * Dd;
  const float* pr = pos + (size_t)s * Dd;
  float* xr = x + (size_t)t * Dd;
  for (int c = threadIdx.x; c < Dd; c += blockDim.x) xr[c] = tr[c] + pr[c];
}

// ---------------- layernorm: f32 in -> bf16 out ----------------
__global__ __launch_bounds__(256) void k_ln(const float* __restrict__ x, const float* __restrict__ g,
                                            const float* __restrict__ b, u16* __restrict__ y){
  int row = blockIdx.x, tid = threadIdx.x;
  const float* xr = x + (size_t)row * Dd;
  float v0 = xr[tid], v1 = xr[tid + 256], v2 = xr[tid + 512];
  float s = v0 + v1 + v2, ss = v0 * v0 + v1 * v1 + v2 * v2;
  for (int o = 1; o < 64; o <<= 1){ s += __shfl_xor(s, o, 64); ss += __shfl_xor(ss, o, 64); }
  __shared__ float red[8];
  int w = tid >> 6, l = tid & 63;
  if (l == 0){ red[w] = s; red[w + 4] = ss; }
  __syncthreads();
  s = red[0] + red[1] + red[2] + red[3];
  ss = red[4] + red[5] + red[6] + red[7];
  float mu = s * (1.0f / Dd);
  float var = ss * (1.0f / Dd) - mu * mu;
  float rs = rsqrtf(var + 1e-5f);
  u16* yr = y + (size_t)row * Dd;
  yr[tid]       = f2bf((v0 - mu) * rs * g[tid]       + b[tid]);
  yr[tid + 256] = f2bf((v1 - mu) * rs * g[tid + 256] + b[tid + 256]);
  yr[tid + 512] = f2bf((v2 - mu) * rs * g[tid + 512] + b[tid + 512]);
}

// ---------------- transpose+convert: f32 [R][C] -> bf16 [C][R] ----------------
__global__ void k_transpose(const float* __restrict__ src, u16* __restrict__ dst,
                            int R, int C, long smat, long dmat){
  __shared__ float tile[32][33];
  src += (size_t)blockIdx.z * smat;
  dst += (size_t)blockIdx.z * dmat;
  int c0 = blockIdx.x * 32, r0 = blockIdx.y * 32;
  int tx = threadIdx.x, ty = threadIdx.y;   // 32 x 8
  #pragma unroll
  for (int i = 0; i < 4; i++){
    int r = r0 + ty + i * 8, c = c0 + tx;
    if (c < C) tile[ty + i * 8][tx] = src[(size_t)r * C + c];
  }
  __syncthreads();
  #pragma unroll
  for (int i = 0; i < 4; i++){
    int c = c0 + ty + i * 8, r = r0 + tx;
    if (c < C) dst[(size_t)c * R + r] = f2bf(tile[tx][ty + i * 8]);
  }
}

// ---------------- pack [bq;bk;bv] per layer into [L][2304] ----------------
__global__ void k_biaspack(const float* __restrict__ bq, const float* __restrict__ bk,
                           const float* __restrict__ bv, float* __restrict__ o){
  int i = blockIdx.x * 256 + threadIdx.x;
  int col = i % NQKV, lay = i / NQKV;
  float v = (col < Dd) ? bq[lay * Dd + col]
          : (col < 2 * Dd) ? bk[lay * Dd + col - Dd]
          : bv[lay * Dd + col - 2 * Dd];
  o[i] = v;
}

// ---------------- combine split-K partials + bias + residual (in-place on x) ----------------
__global__ __launch_bounds__(256) void k_combine(const float* __restrict__ p,
                                                 const float* __restrict__ bias,
                                                 float* __restrict__ x){
  int i = blockIdx.x * 256 + threadIdx.x;          // one float4 group
  f32x4 a  = ((const f32x4*)x)[i];
  f32x4 q0 = ((const f32x4*)p)[i];
  f32x4 q1 = ((const f32x4*)(p + (size_t)Mtok * Dd))[i];
  int col0 = (i * 4) % Dd;
  f32x4 bv = *(const f32x4*)(bias + col0);
  ((f32x4*)x)[i] = a + q0 + q1 + bv;
}

// ---------------- 2-phase counted-vmcnt GEMM ----------------
// C[M=2048, N] = A * Bt^T (both bf16, Bt is [N][K]).
// EPI: 0 head (f32 out, col<Nn bound), 1 qkv (bf16+bias+qscale+fused V-transpose),
//      2 ffn1 (bf16+bias+GELU), 3 wo (f32, +bias+residual in-place on Cf),
//      4 ffn2 split-K partial (f32 to part buffer)
template<int BM, int BN, int EPI>
__global__ __launch_bounds__(256) void k_gemm2(const u16* __restrict__ A, const u16* __restrict__ Bt,
    const float* __restrict__ bias, float* __restrict__ Cf, u16* __restrict__ Cb,
    u16* __restrict__ vt, int Nn, int MT, int NT){
  constexpr bool SPLIT = (EPI == 4);
  constexpr int KST  = SPLIT ? Ff : Dd;       // row stride of A and Bt
  constexpr int KLEN = SPLIT ? (Ff / 2) : Dd; // K range per block
  constexpr int nk = KLEN / 32;               // 48 or 24 (even)
  constexpr int HM = BM / 2, HN = BN / 2, FM = HM / 16, FN = HN / 16;
  constexpr int nA = (BM * 4) / 256, nB = (BN * 4) / 256, NL = nA + nB;
  __shared__ __align__(16) u16 ldsA[2][BM * 32];
  __shared__ __align__(16) u16 ldsB[2][BN * 32];
  int tid = threadIdx.x, wid = tid >> 6, l = tid & 63;
  int wm = wid >> 1, wn = wid & 1;
  int lr = l & 15, lc = l >> 4;
  int nwg = gridDim.x, dIdx = blockIdx.x;
  int L = (dIdx & 7) * (nwg >> 3) + (dIdx >> 3);   // XCD-chunked, nwg%8==0
  int kidx = 0;
  if (SPLIT){ int per = MT * NT; kidx = L / per; L -= kidx * per; }
  int mtile = L % MT, ntile = L / MT;
  int m0 = mtile * BM, n0 = ntile * BN;
  int kbase = kidx * KLEN;

  // staging pointers (bumped +32 per stage) and LDS destinations
  const u16* gAp[nA]; const u16* gBp[nB];
  u16 *dA0[nA], *dA1[nA], *dB0[nB], *dB1[nB];
  #pragma unroll
  for (int i = 0; i < nA; i++){
    int id = i * 256 + tid, row = id >> 2, c = id & 3;
    int cs = c ^ ((row >> 1) & 3);
    gAp[i] = A + (size_t)(m0 + row) * KST + kbase + cs * 8;
    dA0[i] = &ldsA[0][id * 8]; dA1[i] = &ldsA[1][id * 8];
  }
  #pragma unroll
  for (int i = 0; i < nB; i++){
    int id = i * 256 + tid, row = id >> 2, c = id & 3;
    int cs = c ^ ((row >> 1) & 3);
    gBp[i] = Bt + (size_t)(n0 + row) * KST + kbase + cs * 8;
    dB0[i] = &ldsB[0][id * 8]; dB1[i] = &ldsB[1][id * 8];
  }
  // ds-read byte offsets (loop-invariant)
  int offA[FM], offB[FN];
  #pragma unroll
  for (int i = 0; i < FM; i++){
    int row = wm * HM + i * 16 + lr;
    offA[i] = row * 64 + ((lc ^ ((row >> 1) & 3)) << 4);
  }
  #pragma unroll
  for (int j = 0; j < FN; j++){
    int row = wn * HN + j * 16 + lr;
    offB[j] = row * 64 + ((lc ^ ((row >> 1) & 3)) << 4);
  }

  f32x4 acc[FM][FN];
  #pragma unroll
  for (int i = 0; i < FM; i++)
    #pragma unroll
    for (int j = 0; j < FN; j++) acc[i][j] = (f32x4)0.0f;

  auto stage0 = [&]{
    #pragma unroll
    for (int i = 0; i < nA; i++){ gld_lds16(gAp[i], dA0[i]); gAp[i] += 32; }
    #pragma unroll
    for (int i = 0; i < nB; i++){ gld_lds16(gBp[i], dB0[i]); gBp[i] += 32; }
  };
  auto stage1 = [&]{
    #pragma unroll
    for (int i = 0; i < nA; i++){ gld_lds16(gAp[i], dA1[i]); gAp[i] += 32; }
    #pragma unroll
    for (int i = 0; i < nB; i++){ gld_lds16(gBp[i], dB1[i]); gBp[i] += 32; }
  };
  auto compute = [&](const u16* bA, const u16* bB){
    short8 af[FM], bfr[FN];
    #pragma unroll
    for (int i = 0; i < FM; i++) af[i] = *(const short8*)((const char*)bA + offA[i]);
    #pragma unroll
    for (int j = 0; j < FN; j++) bfr[j] = *(const short8*)((const char*)bB + offB[j]);
    __builtin_amdgcn_s_setprio(1);
    #pragma unroll
    for (int i = 0; i < FM; i++)
      #pragma unroll
      for (int j = 0; j < FN; j++)
        acc[i][j] = __builtin_amdgcn_mfma_f32_16x16x32_bf16(af[i], bfr[j], acc[i][j], 0, 0, 0);
    __builtin_amdgcn_s_setprio(0);
  };

  stage0();                                   // step 0
  #pragma unroll 1
  for (int t = 0; t < nk; t += 2){
    __builtin_amdgcn_s_barrier();             // all waves done reading buf1 (step t-1)
    __builtin_amdgcn_sched_barrier(0);
    stage1(); waitv<NL>();                    // stage step t+1; wait step t landed
    __builtin_amdgcn_s_barrier();             // step t visible to all
    __builtin_amdgcn_sched_barrier(0);
    compute(&ldsA[0][0], &ldsB[0][0]);        // step t
    __builtin_amdgcn_s_barrier();             // all waves done reading buf0
    __builtin_amdgcn_sched_barrier(0);
    if (t + 2 < nk){ stage0(); waitv<NL>(); } // stage step t+2; wait step t+1
    else waitv<0>();
    __builtin_amdgcn_s_barrier();
    __builtin_amdgcn_sched_barrier(0);
    compute(&ldsA[1][0], &ldsB[1][0]);        // step t+1
  }

  if (EPI == 4){
    float* P = Cf + (size_t)kidx * Mtok * Dd;
    #pragma unroll
    for (int i = 0; i < FM; i++)
      #pragma unroll
      for (int j = 0; j < FN; j++){
        int col = n0 + wn * HN + j * 16 + lr;
        #pragma unroll
        for (int r = 0; r < 4; r++){
          int row = m0 + wm * HM + i * 16 + lc * 4 + r;
          P[(size_t)row * Dd + col] = acc[i][j][r];
        }
      }
    return;
  }
  #pragma unroll
  for (int i = 0; i < FM; i++){
    #pragma unroll
    for (int j = 0; j < FN; j++){
      int col = n0 + wn * HN + j * 16 + lr;
      if (EPI == 0 && col >= Nn) continue;
      float bv = (EPI == 1 || EPI == 2 || EPI == 3) ? bias[col] : 0.0f;
      #pragma unroll
      for (int r = 0; r < 4; r++){
        int row = m0 + wm * HM + i * 16 + lc * 4 + r;
        float v = acc[i][j][r] + bv;
        if (EPI == 1){ if (col < Dd) v *= 0.125f; }
        if (EPI == 2) v = 0.5f * v * (1.0f + erff(v * 0.70710678118f));
        if (EPI == 0){
          Cf[(size_t)row * Nn + col] = v;
        } else if (EPI == 3){
          Cf[(size_t)row * Nn + col] += v;      // residual in-place
        } else {
          u16 bvv = f2bf(v);
          Cb[(size_t)row * Nn + col] = bvv;
          if (EPI == 1 && col >= 2 * Dd){        // fused V-transpose -> vt[bh][d][s]
            int c2 = col - 2 * Dd, hh = c2 >> 6, dd2 = c2 & 63;
            int bb = row >> 10, ss2 = row & 1023;
            vt[((size_t)((bb * Hh + hh) * DHh + dd2) << 10) + ss2] = bvv;
          }
        }
      }
    }
  }
}

// ---------------- flash-style causal attention, no K/V staging (L2-resident) ----------------
// grid: (S/64, B*H). 4 waves, each owns 16 q rows. KV blocks of 64. No block barriers.
__global__ __launch_bounds__(256) void k_attn(const u16* __restrict__ qkv, const u16* __restrict__ vt,
                                              u16* __restrict__ o){
  __shared__ __align__(16) u16 ldsP[4][16 * 72];   // per-wave 16 x 64 (rows padded to 144B)
  int iq = blockIdx.x, bh = blockIdx.y, b = bh / Hh, h = bh % Hh;
  int tid = threadIdx.x, wid = tid >> 6, l = tid & 63, lr = l & 15, lc = l >> 4;
  int qrow = b * Ss + iq * 64 + wid * 16 + lr;
  const u16* qp = qkv + (size_t)qrow * NQKV + h * DHh;
  short8 qf0 = *(const short8*)(qp + lc * 8);
  short8 qf1 = *(const short8*)(qp + 32 + lc * 8);
  // per-lane K/V base pointers
  const u16* kl = qkv + ((size_t)b * Ss) * NQKV + Dd + h * DHh + (size_t)lr * NQKV + lc * 8;
  const u16* vl = vt + ((size_t)(bh * DHh) + lr) * Ss + lc * 8;
  float mreg[4], lsum[4];
  f32x4 oacc[4];
  #pragma unroll
  for (int r = 0; r < 4; r++){ mreg[r] = -1e30f; lsum[r] = 0.0f; }
  #pragma unroll
  for (int i = 0; i < 4; i++) oacc[i] = (f32x4)0.0f;
  u16* pbase = ldsP[wid];
  for (int j = 0; j <= iq; ++j){
    const u16* kj = kl + (size_t)(j * 64) * NQKV;
    const u16* vj = vl + j * 64;
    short8 kf[4][2];
    #pragma unroll
    for (int fn = 0; fn < 4; fn++){
      kf[fn][0] = *(const short8*)(kj + (size_t)(fn * 16) * NQKV);
      kf[fn][1] = *(const short8*)(kj + (size_t)(fn * 16) * NQKV + 32);
    }
    f32x4 sc[4];
    #pragma unroll
    for (int fn = 0; fn < 4; fn++) sc[fn] = (f32x4)0.0f;
    #pragma unroll
    for (int fn = 0; fn < 4; fn++){
      sc[fn] = __builtin_amdgcn_mfma_f32_16x16x32_bf16(qf0, kf[fn][0], sc[fn], 0, 0, 0);
      sc[fn] = __builtin_amdgcn_mfma_f32_16x16x32_bf16(qf1, kf[fn][1], sc[fn], 0, 0, 0);
    }
    if (j == iq){
      #pragma unroll
      for (int fn = 0; fn < 4; fn++){
        int kv = fn * 16 + lr;
        #pragma unroll
        for (int r = 0; r < 4; r++){
          int qr = wid * 16 + lc * 4 + r;
          if (kv > qr) sc[fn][r] = -1e30f;
        }
      }
    }
    float alpha[4];
    #pragma unroll
    for (int r = 0; r < 4; r++){
      float mx = fmaxf(fmaxf(sc[0][r], sc[1][r]), fmaxf(sc[2][r], sc[3][r]));
      mx = fmaxf(mx, __shfl_xor(mx, 1, 64));
      mx = fmaxf(mx, __shfl_xor(mx, 2, 64));
      mx = fmaxf(mx, __shfl_xor(mx, 4, 64));
      mx = fmaxf(mx, __shfl_xor(mx, 8, 64));
      float mnew = fmaxf(mreg[r], mx);
      alpha[r] = __expf(mreg[r] - mnew);
      mreg[r] = mnew;
      float rsum = 0.0f;
      #pragma unroll
      for (int fn = 0; fn < 4; fn++){
        float p = __expf(sc[fn][r] - mnew);
        sc[fn][r] = p;
        rsum += p;
      }
      rsum += __shfl_xor(rsum, 1, 64);
      rsum += __shfl_xor(rsum, 2, 64);
      rsum += __shfl_xor(rsum, 4, 64);
      rsum += __shfl_xor(rsum, 8, 64);
      lsum[r] = lsum[r] * alpha[r] + rsum;
    }
    #pragma unroll
    for (int fn = 0; fn < 4; fn++)
      #pragma unroll
      for (int r = 0; r < 4; r++)
        pbase[(lc * 4 + r) * 72 + fn * 16 + lr] = f2bf(sc[fn][r]);
    asm volatile("s_waitcnt lgkmcnt(0)" ::: "memory");   // P writes visible to own wave reads
    __builtin_amdgcn_sched_barrier(0);
    #pragma unroll
    for (int fd = 0; fd < 4; fd++)
      #pragma unroll
      for (int r = 0; r < 4; r++) oacc[fd][r] *= alpha[r];
    short8 pa0 = *(const short8*)((const char*)pbase + lr * 144 + lc * 16);
    short8 pa1 = *(const short8*)((const char*)pbase + lr * 144 + (4 + lc) * 16);
    #pragma unroll
    for (int fd = 0; fd < 4; fd++){
      short8 vf0 = *(const short8*)(vj + (size_t)(fd * 16) * Ss);
      short8 vf1 = *(const short8*)(vj + (size_t)(fd * 16) * Ss + 32);
      oacc[fd] = __builtin_amdgcn_mfma_f32_16x16x32_bf16(pa0, vf0, oacc[fd], 0, 0, 0);
      oacc[fd] = __builtin_amdgcn_mfma_f32_16x16x32_bf16(pa1, vf1, oacc[fd], 0, 0, 0);
    }
  }
  #pragma unroll
  for (int fd = 0; fd < 4; fd++)
    #pragma unroll
    for (int r = 0; r < 4; r++){
      int row = b * Ss + iq * 64 + wid * 16 + lc * 4 + r;
      o[(size_t)row * Dd + h * DHh + fd * 16 + lr] = f2bf(oacc[fd][r] / lsum[r]);
    }
}

// ---------------- host ----------------
extern "C" void kernel_launch(void* const* d_in, const int* in_sizes, int n_in,
                              void* d_out, int out_size, void* d_ws, size_t ws_size,
                              hipStream_t stream){
  const int*   ids  = (const int*)d_in[0];
  const float* tok  = (const float*)d_in[1];
  const float* pos  = (const float*)d_in[2];
  const float* Wq   = (const float*)d_in[3];
  const float* bq   = (const float*)d_in[4];
  const float* Wk   = (const float*)d_in[5];
  const float* bk   = (const float*)d_in[6];
  const float* Wv   = (const float*)d_in[7];
  const float* bv   = (const float*)d_in[8];
  const float* Wo   = (const float*)d_in[9];
  const float* bo   = (const float*)d_in[10];
  const float* ln1g = (const float*)d_in[11];
  const float* ln1b = (const float*)d_in[12];
  const float* ln2g = (const float*)d_in[13];
  const float* ln2b = (const float*)d_in[14];
  const float* W1   = (const float*)d_in[15];
  const float* b1   = (const float*)d_in[16];
  const float* W2   = (const float*)d_in[17];
  const float* b2   = (const float*)d_in[18];
  const float* lnfg = (const float*)d_in[19];
  const float* lnfb = (const float*)d_in[20];
  const float* Wh   = (const float*)d_in[21];
  float* out = (float*)d_out;

  auto al = [](size_t x){ return (x + 255) & ~(size_t)255; };
  size_t off = 0;
  auto take = [&](size_t bytes){ size_t r = off; off = al(off + bytes); return r; };
  size_t o_x    = take((size_t)Mtok * Dd * 4);
  size_t o_h    = take((size_t)Mtok * Dd * 2);
  size_t o_qkv  = take((size_t)Mtok * NQKV * 2);
  size_t o_vt   = take((size_t)Bbatch * Hh * DHh * Ss * 2);
  size_t o_o    = take((size_t)Mtok * Dd * 2);
  size_t o_mid  = take((size_t)Mtok * Ff * 2);
  size_t o_bq   = take((size_t)Ll * NQKV * 4);
  size_t o_part = take((size_t)2 * Mtok * Dd * 4);
  size_t o_rot = off;
  size_t o_wqkv, o_wo, o_w1, o_w2, o_wh;
  bool full;
  {
    size_t t = off;
    o_wqkv = t; t = al(t + (size_t)Ll * NQKV * Dd * 2);
    o_wo   = t; t = al(t + (size_t)Ll * Dd * Dd * 2);
    o_w1   = t; t = al(t + (size_t)Ll * Ff * Dd * 2);
    o_w2   = t; t = al(t + (size_t)Ll * Dd * Ff * 2);
    o_wh   = t; t = al(t + (size_t)VPAD * Dd * 2);
    full = (t <= ws_size);
  }
  char* ws = (char*)d_ws;
  float* x    = (float*)(ws + o_x);
  u16*   h    = (u16*)(ws + o_h);
  u16*   qkvb = (u16*)(ws + o_qkv);
  u16*   vtb  = (u16*)(ws + o_vt);
  u16*   ob   = (u16*)(ws + o_o);
  u16*   midb = (u16*)(ws + o_mid);
  float* bqkvp= (float*)(ws + o_bq);
  float* part = (float*)(ws + o_part);
  u16* wqkvT = full ? (u16*)(ws + o_wqkv) : (u16*)(ws + o_rot);
  u16* woT   = full ? (u16*)(ws + o_wo)   : (u16*)(ws + o_rot);
  u16* w1T   = full ? (u16*)(ws + o_w1)   : (u16*)(ws + o_rot);
  u16* w2T   = full ? (u16*)(ws + o_w2)   : (u16*)(ws + o_rot);
  u16* whT   = full ? (u16*)(ws + o_wh)   : (u16*)(ws + o_rot);

  dim3 tb(32, 8);
  auto tpose = [&](const float* src, u16* dst, int R, int C, int nmat, long smat, long dmat){
    k_transpose<<<dim3((C + 31) / 32, R / 32, nmat), tb, 0, stream>>>(src, dst, R, C, smat, dmat);
  };

  k_biaspack<<<(Ll * NQKV) / 256, 256, 0, stream>>>(bq, bk, bv, bqkvp);
  k_embed<<<Mtok, 256, 0, stream>>>(ids, tok, pos, x);

  if (full){
    tpose(Wq, wqkvT,              Dd, Dd, Ll, (long)Dd * Dd, (long)NQKV * Dd);
    tpose(Wk, wqkvT + Dd * Dd,    Dd, Dd, Ll, (long)Dd * Dd, (long)NQKV * Dd);
    tpose(Wv, wqkvT + 2 * Dd * Dd,Dd, Dd, Ll, (long)Dd * Dd, (long)NQKV * Dd);
    tpose(Wo, woT, Dd, Dd, Ll, (long)Dd * Dd, (long)Dd * Dd);
    tpose(W1, w1T, Dd, Ff, Ll, (long)Dd * Ff, (long)Ff * Dd);
    tpose(W2, w2T, Ff, Dd, Ll, (long)Ff * Dd, (long)Dd * Ff);
    tpose(Wh, whT, Dd, Vv, 1, 0, 0);
  }

  // all grids 1D, nwg % 8 == 0
  auto gemm_qkv = [&](const u16* Aop, const u16* Bop, const float* bias, u16* Cb){
    constexpr int MT = Mtok / 64, NT = NQKV / 128;          // 32 x 18 = 576
    k_gemm2<64, 128, 1><<<MT * NT, 256, 0, stream>>>(Aop, Bop, bias, nullptr, Cb, vtb, NQKV, MT, NT);
  };
  auto gemm_wo = [&](const u16* Aop, const u16* Bop, const float* bias, float* C){
    constexpr int MT = Mtok / 64, NT = Dd / 64;              // 32 x 12 = 384
    k_gemm2<64, 64, 3><<<MT * NT, 256, 0, stream>>>(Aop, Bop, bias, C, nullptr, nullptr, Dd, MT, NT);
  };
  auto gemm_ffn1 = [&](const u16* Aop, const u16* Bop, const float* bias, u16* Cb){
    constexpr int MT = Mtok / 64, NT = Ff / 128;             // 32 x 24 = 768
    k_gemm2<64, 128, 2><<<MT * NT, 256, 0, stream>>>(Aop, Bop, bias, nullptr, Cb, nullptr, Ff, MT, NT);
  };
  auto gemm_ffn2 = [&](const u16* Aop, const u16* Bop){
    constexpr int MT = Mtok / 64, NT = Dd / 64;              // 32 x 12 x 2 = 768
    k_gemm2<64, 64, 4><<<MT * NT * 2, 256, 0, stream>>>(Aop, Bop, nullptr, part, nullptr, nullptr, Dd, MT, NT);
  };
  auto gemm_head = [&](const u16* Aop, const u16* Bop, float* C){
    constexpr int MT = Mtok / 128, NT = VPAD / 128;          // 16 x 393 = 6288
    k_gemm2<128, 128, 0><<<MT * NT, 256, 0, stream>>>(Aop, Bop, nullptr, C, nullptr, nullptr, Vv, MT, NT);
  };

  for (int l = 0; l < Ll; ++l){
    const u16* wqkvL = full ? wqkvT + (size_t)l * NQKV * Dd : wqkvT;
    const u16* woL   = full ? woT   + (size_t)l * Dd * Dd   : woT;
    const u16* w1L   = full ? w1T   + (size_t)l * Ff * Dd   : w1T;
    const u16* w2L   = full ? w2T   + (size_t)l * Dd * Ff   : w2T;
    if (!full){
      tpose(Wq + (size_t)l * Dd * Dd, wqkvT,              Dd, Dd, 1, 0, 0);
      tpose(Wk + (size_t)l * Dd * Dd, wqkvT + Dd * Dd,    Dd, Dd, 1, 0, 0);
      tpose(Wv + (size_t)l * Dd * Dd, wqkvT + 2 * Dd * Dd,Dd, Dd, 1, 0, 0);
    }
    k_ln<<<Mtok, 256, 0, stream>>>(x, ln1g + l * Dd, ln1b + l * Dd, h);
    gemm_qkv(h, wqkvL, bqkvp + l * NQKV, qkvb);
    k_attn<<<dim3(Ss / 64, Bbatch * Hh), 256, 0, stream>>>(qkvb, vtb, ob);
    if (!full) tpose(Wo + (size_t)l * Dd * Dd, woT, Dd, Dd, 1, 0, 0);
    gemm_wo(ob, woL, bo + l * Dd, x);
    k_ln<<<Mtok, 256, 0, stream>>>(x, ln2g + l * Dd, ln2b + l * Dd, h);
    if (!full) tpose(W1 + (size_t)l * Dd * Ff, w1T, Dd, Ff, 1, 0, 0);
    gemm_ffn1(h, w1L, b1 + l * Ff, midb);
    if (!full) tpose(W2 + (size_t)l * Ff * Dd, w2T, Ff, Dd, 1, 0, 0);
    gemm_ffn2(midb, w2L);
    k_combine<<<(Mtok * Dd / 4) / 256, 256, 0, stream>>>(part, b2 + l * Dd, x);
  }
  k_ln<<<Mtok, 256, 0, stream>>>(x, lnfg, lnfb, h);
  if (!full) tpose(Wh, whT, Dd, Vv, 1, 0, 0);
  gemm_head(h, whT, out);
}

// Round 6
// 2307.523 us; speedup vs baseline: 1.1346x; 1.1346x over previous
//
#include <hip/hip_runtime.h>
#include <hip/hip_bf16.h>
#include <cstdint>
#include <cstddef>

#define DEV __device__ __forceinline__

typedef __attribute__((ext_vector_type(8))) short short8;   // 8 bf16 (4 VGPR)
typedef __attribute__((ext_vector_type(4))) short s16x4;
typedef __attribute__((ext_vector_type(4))) float f32x4;
typedef unsigned short u16;
typedef unsigned int u32;

static constexpr int Vv = 50257;
static constexpr int Dd = 768;
static constexpr int Ll = 12;
static constexpr int Hh = 12;
static constexpr int Ff = 3072;
static constexpr int Ss = 1024;
static constexpr int Bbatch = 2;
static constexpr int DHh = 64;
static constexpr int Mtok = Bbatch * Ss;   // 2048
static constexpr int NQKV = 3 * Dd;        // 2304
static constexpr int VPAD = 50304;         // 50257 padded to 128-multiple

DEV u16 f2bf(float f){ u32 x; __builtin_memcpy(&x, &f, 4); x += 0x7fffu + ((x >> 16) & 1u); return (u16)(x >> 16); }

DEV void gld_lds16(const void* g, void* l){
  __builtin_amdgcn_global_load_lds((const __attribute__((address_space(1))) void*)g,
                                   (__attribute__((address_space(3))) void*)l, 16, 0, 0);
}

template<int N> DEV void waitv(){
  if constexpr (N == 0) asm volatile("s_waitcnt vmcnt(0)" ::: "memory");
  else if constexpr (N == 2) asm volatile("s_waitcnt vmcnt(2)" ::: "memory");
  else if constexpr (N == 3) asm volatile("s_waitcnt vmcnt(3)" ::: "memory");
  else if constexpr (N == 4) asm volatile("s_waitcnt vmcnt(4)" ::: "memory");
}
DEV void barrier_sb(){
  __builtin_amdgcn_s_barrier();
  __builtin_amdgcn_sched_barrier(0);
}

// ---------------- embedding ----------------
__global__ void k_embed(const int* __restrict__ ids, const float* __restrict__ tok,
                        const float* __restrict__ pos, float* __restrict__ x){
  int t = blockIdx.x;
  int id = ids[t];
  int s = t & (Ss - 1);
  const float* tr = tok + (size_t)id * Dd;
  const float* pr = pos + (size_t)s * Dd;
  float* xr = x + (size_t)t * Dd;
  for (int c = threadIdx.x; c < Dd; c += blockDim.x) xr[c] = tr[c] + pr[c];
}

// ---------------- layernorm: f32 in -> bf16 out ----------------
__global__ __launch_bounds__(256) void k_ln(const float* __restrict__ x, const float* __restrict__ g,
                                            const float* __restrict__ b, u16* __restrict__ y){
  int row = blockIdx.x, tid = threadIdx.x;
  const float* xr = x + (size_t)row * Dd;
  float v0 = xr[tid], v1 = xr[tid + 256], v2 = xr[tid + 512];
  float s = v0 + v1 + v2, ss = v0 * v0 + v1 * v1 + v2 * v2;
  for (int o = 1; o < 64; o <<= 1){ s += __shfl_xor(s, o, 64); ss += __shfl_xor(ss, o, 64); }
  __shared__ float red[8];
  int w = tid >> 6, l = tid & 63;
  if (l == 0){ red[w] = s; red[w + 4] = ss; }
  __syncthreads();
  s = red[0] + red[1] + red[2] + red[3];
  ss = red[4] + red[5] + red[6] + red[7];
  float mu = s * (1.0f / Dd);
  float var = ss * (1.0f / Dd) - mu * mu;
  float rs = rsqrtf(var + 1e-5f);
  u16* yr = y + (size_t)row * Dd;
  yr[tid]       = f2bf((v0 - mu) * rs * g[tid]       + b[tid]);
  yr[tid + 256] = f2bf((v1 - mu) * rs * g[tid + 256] + b[tid + 256]);
  yr[tid + 512] = f2bf((v2 - mu) * rs * g[tid + 512] + b[tid + 512]);
}

// ---------------- transpose+convert: f32 [R][C] -> bf16 [C][R], 64r x 32c tiles ----------------
__global__ __launch_bounds__(256) void k_transpose(const float* __restrict__ src, u16* __restrict__ dst,
                                                   int R, int C, long smat, long dmat){
  __shared__ float tile[64][33];
  src += (size_t)blockIdx.z * smat;
  dst += (size_t)blockIdx.z * dmat;
  int c0 = blockIdx.x * 32, r0 = blockIdx.y * 64;
  int tid = threadIdx.x;
  int tc = tid & 31, tr = tid >> 5;
  #pragma unroll
  for (int i = 0; i < 8; i++){
    int r = tr + i * 8, c = c0 + tc;
    tile[r][tc] = (c < C) ? src[(size_t)(r0 + r) * C + c] : 0.0f;
  }
  __syncthreads();
  #pragma unroll
  for (int it = 0; it < 2; it++){
    int id = it * 256 + tid;
    int c = id & 31, rg = id >> 5, r = rg * 4;
    int cc = c0 + c;
    if (cc < C){
      s16x4 v = { (short)f2bf(tile[r][c]), (short)f2bf(tile[r + 1][c]),
                  (short)f2bf(tile[r + 2][c]), (short)f2bf(tile[r + 3][c]) };
      *(s16x4*)(dst + (size_t)cc * R + r0 + r) = v;
    }
  }
}

// ---------------- pack [bq;bk;bv] per layer into [L][2304] ----------------
__global__ void k_biaspack(const float* __restrict__ bq, const float* __restrict__ bk,
                           const float* __restrict__ bv, float* __restrict__ o){
  int i = blockIdx.x * 256 + threadIdx.x;
  int col = i % NQKV, lay = i / NQKV;
  float v = (col < Dd) ? bq[lay * Dd + col]
          : (col < 2 * Dd) ? bk[lay * Dd + col - Dd]
          : bv[lay * Dd + col - 2 * Dd];
  o[i] = v;
}

// ---------------- combine 4 split-K partials + bias + residual (in-place on x) ----------------
__global__ __launch_bounds__(256) void k_combine(const float* __restrict__ p,
                                                 const float* __restrict__ bias,
                                                 float* __restrict__ x){
  int i = blockIdx.x * 256 + threadIdx.x;          // one float4 group
  constexpr size_t SL = (size_t)Mtok * Dd;
  f32x4 a  = ((const f32x4*)x)[i];
  f32x4 q0 = ((const f32x4*)p)[i];
  f32x4 q1 = ((const f32x4*)(p + SL))[i];
  f32x4 q2 = ((const f32x4*)(p + 2 * SL))[i];
  f32x4 q3 = ((const f32x4*)(p + 3 * SL))[i];
  int col0 = (i * 4) % Dd;
  f32x4 bv = *(const f32x4*)(bias + col0);
  ((f32x4*)x)[i] = a + (q0 + q1) + (q2 + q3) + bv;
}

// ---------------- 3-buffer ring, 1 barrier + 1 counted vmcnt per K-step ----------------
// C[M=2048, N] = A * Bt^T (bf16 operands, Bt is [N][K-stride]). KLEN = 768 always (nk=24).
// EPI: 0 head (f32), 1 qkv (bf16+bias+qscale+fused V-transpose), 2 ffn1 (bf16+bias+GELU),
//      3 wo (f32 +bias+residual in-place), 4 ffn2 split-K=4 partial (f32)
template<int BM, int BN, int STRIDE, int EPI>
__global__ __launch_bounds__(256) void k_gemm3(const u16* __restrict__ A, const u16* __restrict__ Bt,
    const float* __restrict__ bias, float* __restrict__ Cf, u16* __restrict__ Cb,
    u16* __restrict__ vt, int Nn, int MT, int NT){
  constexpr int HM = BM / 2, HN = BN / 2, FM = HM / 16, FN = HN / 16;
  constexpr int nA = (BM * 4) / 256, nB = (BN * 4) / 256, NL = nA + nB;
  constexpr int ABUF = BM * 32, BBUF = BN * 32;      // u16 elements per buffer
  __shared__ __align__(16) u16 ldsA[3 * ABUF];
  __shared__ __align__(16) u16 ldsB[3 * BBUF];
  int tid = threadIdx.x, wid = tid >> 6, l = tid & 63;
  int wm = wid >> 1, wn = wid & 1;
  int lr = l & 15, lc = l >> 4;
  int nwg = gridDim.x, dIdx = blockIdx.x;
  int L = (dIdx & 7) * (nwg >> 3) + (dIdx >> 3);     // XCD-chunked, nwg % 8 == 0
  int kidx = 0;
  if (EPI == 4){ int per = MT * NT; kidx = L / per; L -= kidx * per; }
  int mtile = L % MT, ntile = L / MT;
  int m0 = mtile * BM, n0 = ntile * BN;
  int kbase = kidx * 768;

  const u16* gA[nA]; u16* dA[nA];
  const u16* gB[nB]; u16* dB[nB];
  #pragma unroll
  for (int i = 0; i < nA; i++){
    int id = i * 256 + tid, row = id >> 2, c = id & 3;
    int cs = c ^ ((row >> 1) & 3);
    gA[i] = A + (size_t)(m0 + row) * STRIDE + kbase + cs * 8;
    dA[i] = ldsA + id * 8;
  }
  #pragma unroll
  for (int i = 0; i < nB; i++){
    int id = i * 256 + tid, row = id >> 2, c = id & 3;
    int cs = c ^ ((row >> 1) & 3);
    gB[i] = Bt + (size_t)(n0 + row) * STRIDE + kbase + cs * 8;
    dB[i] = ldsB + id * 8;
  }
  int offA[FM], offB[FN];
  #pragma unroll
  for (int i = 0; i < FM; i++){
    int row = wm * HM + i * 16 + lr;
    offA[i] = row * 64 + ((lc ^ ((row >> 1) & 3)) << 4);
  }
  #pragma unroll
  for (int j = 0; j < FN; j++){
    int row = wn * HN + j * 16 + lr;
    offB[j] = row * 64 + ((lc ^ ((row >> 1) & 3)) << 4);
  }

  f32x4 acc[FM][FN];
  #pragma unroll
  for (int i = 0; i < FM; i++)
    #pragma unroll
    for (int j = 0; j < FN; j++) acc[i][j] = (f32x4)0.0f;

  auto stage = [&](int buf){                  // buf literal at all call sites
    #pragma unroll
    for (int i = 0; i < nA; i++){ gld_lds16(gA[i], dA[i] + buf * ABUF); gA[i] += 32; }
    #pragma unroll
    for (int i = 0; i < nB; i++){ gld_lds16(gB[i], dB[i] + buf * BBUF); gB[i] += 32; }
  };
  auto compute = [&](int buf){
    const char* bA = (const char*)(ldsA + buf * ABUF);
    const char* bB = (const char*)(ldsB + buf * BBUF);
    short8 af[FM], bfr[FN];
    #pragma unroll
    for (int i = 0; i < FM; i++) af[i] = *(const short8*)(bA + offA[i]);
    #pragma unroll
    for (int j = 0; j < FN; j++) bfr[j] = *(const short8*)(bB + offB[j]);
    __builtin_amdgcn_s_setprio(1);
    #pragma unroll
    for (int i = 0; i < FM; i++)
      #pragma unroll
      for (int j = 0; j < FN; j++)
        acc[i][j] = __builtin_amdgcn_mfma_f32_16x16x32_bf16(af[i], bfr[j], acc[i][j], 0, 0, 0);
    __builtin_amdgcn_s_setprio(0);
  };

  // nk = 24.  stage(t) for t=0,1 in prologue; loop t=0..20 unrolled x3; tail t=21,22,23.
  stage(0); stage(1);
  waitv<NL>(); barrier_sb();                   // tile 0 landed (tile 1 may fly)
  #pragma unroll 1
  for (int tt = 0; tt < 21; tt += 3){
    stage(2); compute(0); waitv<NL>(); barrier_sb();
    stage(0); compute(1); waitv<NL>(); barrier_sb();
    stage(1); compute(2); waitv<NL>(); barrier_sb();
  }
  stage(2); compute(0); waitv<NL>(); barrier_sb();   // t=21 (stages tile 23)
  compute(1); waitv<0>(); barrier_sb();              // t=22
  compute(2);                                        // t=23

  if (EPI == 4){
    float* P = Cf + (size_t)kidx * Mtok * Dd;
    #pragma unroll
    for (int i = 0; i < FM; i++)
      #pragma unroll
      for (int j = 0; j < FN; j++){
        int col = n0 + wn * HN + j * 16 + lr;
        #pragma unroll
        for (int r = 0; r < 4; r++){
          int row = m0 + wm * HM + i * 16 + lc * 4 + r;
          P[(size_t)row * Dd + col] = acc[i][j][r];
        }
      }
    return;
  }
  #pragma unroll
  for (int i = 0; i < FM; i++){
    #pragma unroll
    for (int j = 0; j < FN; j++){
      int col = n0 + wn * HN + j * 16 + lr;
      if (EPI == 0 && col >= Nn) continue;
      float bv = (EPI == 1 || EPI == 2 || EPI == 3) ? bias[col] : 0.0f;
      u16 q4[4];
      #pragma unroll
      for (int r = 0; r < 4; r++){
        int row = m0 + wm * HM + i * 16 + lc * 4 + r;
        float v = acc[i][j][r] + bv;
        if (EPI == 1){ if (col < Dd) v *= 0.125f; }
        if (EPI == 2) v = 0.5f * v * (1.0f + erff(v * 0.70710678118f));
        if (EPI == 0){
          Cf[(size_t)row * Nn + col] = v;
        } else if (EPI == 3){
          Cf[(size_t)row * Nn + col] += v;
        } else {
          u16 bvv = f2bf(v);
          q4[r] = bvv;
          Cb[(size_t)row * Nn + col] = bvv;
        }
      }
      if (EPI == 1 && col >= 2 * Dd){            // fused V-transpose -> vt[bh][d][s]
        int c2 = col - 2 * Dd, hh = c2 >> 6, dd2 = c2 & 63;
        int rowb = m0 + wm * HM + i * 16 + lc * 4;
        int bb = rowb >> 10, ss2 = rowb & 1023;
        s16x4 v4 = { (short)q4[0], (short)q4[1], (short)q4[2], (short)q4[3] };
        *(s16x4*)(vt + (((size_t)((bb * Hh + hh) * DHh + dd2)) << 10) + ss2) = v4;
      }
    }
  }
}

// ---------------- flash-style causal attention, 3-buf staged K/V, 1 barrier/tile ----------------
// grid: (S/64, B*H). 4 waves, each owns 16 q rows. KV tiles of 64.
__global__ __launch_bounds__(256) void k_attn(const u16* __restrict__ qkv, const u16* __restrict__ vt,
                                              u16* __restrict__ o){
  constexpr int KB = 64 * 64;                  // u16 elems per K (or V) buffer
  __shared__ __align__(16) u16 ldsK[3 * KB];
  __shared__ __align__(16) u16 ldsV[3 * KB];
  __shared__ __align__(16) u16 ldsP[4][16 * 72];
  int iq = blockIdx.x, bh = blockIdx.y, b = bh / Hh, h = bh % Hh;
  int tid = threadIdx.x, wid = tid >> 6, l = tid & 63, lr = l & 15, lc = l >> 4;
  int nt = iq + 1;
  int qrow = b * Ss + iq * 64 + wid * 16 + lr;
  const u16* qp = qkv + (size_t)qrow * NQKV + h * DHh;
  short8 qf0 = *(const short8*)(qp + lc * 8);
  short8 qf1 = *(const short8*)(qp + 32 + lc * 8);

  // staging: id = c*256+tid, row=id>>3, ch=id&7, swizzle cs = ch ^ (row&7)
  const u16* gK[2]; const u16* gV[2]; u16* dK[2]; u16* dV[2];
  #pragma unroll
  for (int c = 0; c < 2; c++){
    int id = c * 256 + tid, row = id >> 3, ch = id & 7;
    int cs = ch ^ (row & 7);
    gK[c] = qkv + (size_t)(b * Ss + row) * NQKV + Dd + h * DHh + cs * 8;
    gV[c] = vt + ((size_t)(bh * DHh) + row) * Ss + cs * 8;
    dK[c] = ldsK + id * 8;
    dV[c] = ldsV + id * 8;
  }
  auto stage = [&](int soff){                  // soff = buf * KB (runtime)
    #pragma unroll
    for (int c = 0; c < 2; c++){ gld_lds16(gK[c], dK[c] + soff); gK[c] += (size_t)64 * NQKV; }
    #pragma unroll
    for (int c = 0; c < 2; c++){ gld_lds16(gV[c], dV[c] + soff); gV[c] += 64; }
  };
  // ds-read byte offsets (add cb*2 at runtime)
  int koff[4][2], voff[4][2];
  #pragma unroll
  for (int fn = 0; fn < 4; fn++){
    int kv = fn * 16 + lr;
    #pragma unroll
    for (int ks = 0; ks < 2; ks++){
      int ch = ks * 4 + lc;
      koff[fn][ks] = kv * 128 + ((ch ^ (kv & 7)) << 4);
      voff[fn][ks] = koff[fn][ks];             // same geometry for V
    }
  }

  float mreg[4], lsum[4];
  f32x4 oacc[4];
  #pragma unroll
  for (int r = 0; r < 4; r++){ mreg[r] = -1e30f; lsum[r] = 0.0f; }
  #pragma unroll
  for (int i = 0; i < 4; i++) oacc[i] = (f32x4)0.0f;
  u16* pbase = ldsP[wid];

  if (nt > 1){ stage(0); stage(KB); waitv<4>(); }
  else       { stage(0); waitv<0>(); }
  barrier_sb();

  int cb = 0;                                  // compute buffer elem offset: 0, KB, 2KB rotate
  #pragma unroll 1
  for (int t = 0; t < nt; ++t){
    int sb = (cb >= KB) ? (cb - KB) : (cb + 2 * KB);   // (t+2)%3 buffer
    if (t + 2 < nt) stage(sb);
    const char* kbse = (const char*)ldsK + cb * 2;
    const char* vbse = (const char*)ldsV + cb * 2;
    f32x4 sc[4];
    #pragma unroll
    for (int fn = 0; fn < 4; fn++) sc[fn] = (f32x4)0.0f;
    #pragma unroll
    for (int fn = 0; fn < 4; fn++){
      short8 kf0 = *(const short8*)(kbse + koff[fn][0]);
      short8 kf1 = *(const short8*)(kbse + koff[fn][1]);
      sc[fn] = __builtin_amdgcn_mfma_f32_16x16x32_bf16(qf0, kf0, sc[fn], 0, 0, 0);
      sc[fn] = __builtin_amdgcn_mfma_f32_16x16x32_bf16(qf1, kf1, sc[fn], 0, 0, 0);
    }
    if (t == iq){
      #pragma unroll
      for (int fn = 0; fn < 4; fn++){
        int kv = fn * 16 + lr;
        #pragma unroll
        for (int r = 0; r < 4; r++){
          int qr = wid * 16 + lc * 4 + r;
          if (kv > qr) sc[fn][r] = -1e30f;
        }
      }
    }
    float alpha[4];
    #pragma unroll
    for (int r = 0; r < 4; r++){
      float mx = fmaxf(fmaxf(sc[0][r], sc[1][r]), fmaxf(sc[2][r], sc[3][r]));
      mx = fmaxf(mx, __shfl_xor(mx, 1, 64));
      mx = fmaxf(mx, __shfl_xor(mx, 2, 64));
      mx = fmaxf(mx, __shfl_xor(mx, 4, 64));
      mx = fmaxf(mx, __shfl_xor(mx, 8, 64));
      float mnew = fmaxf(mreg[r], mx);
      alpha[r] = __expf(mreg[r] - mnew);
      mreg[r] = mnew;
      float rsum = 0.0f;
      #pragma unroll
      for (int fn = 0; fn < 4; fn++){
        float p = __expf(sc[fn][r] - mnew);
        sc[fn][r] = p;
        rsum += p;
      }
      rsum += __shfl_xor(rsum, 1, 64);
      rsum += __shfl_xor(rsum, 2, 64);
      rsum += __shfl_xor(rsum, 4, 64);
      rsum += __shfl_xor(rsum, 8, 64);
      lsum[r] = lsum[r] * alpha[r] + rsum;
    }
    #pragma unroll
    for (int fn = 0; fn < 4; fn++)
      #pragma unroll
      for (int r = 0; r < 4; r++)
        pbase[(lc * 4 + r) * 72 + fn * 16 + lr] = f2bf(sc[fn][r]);
    asm volatile("s_waitcnt lgkmcnt(0)" ::: "memory");
    __builtin_amdgcn_sched_barrier(0);
    #pragma unroll
    for (int fd = 0; fd < 4; fd++)
      #pragma unroll
      for (int r = 0; r < 4; r++) oacc[fd][r] *= alpha[r];
    short8 pa0 = *(const short8*)((const char*)pbase + lr * 144 + lc * 16);
    short8 pa1 = *(const short8*)((const char*)pbase + lr * 144 + (4 + lc) * 16);
    #pragma unroll
    for (int fd = 0; fd < 4; fd++){
      short8 vf0 = *(const short8*)(vbse + voff[fd][0]);
      short8 vf1 = *(const short8*)(vbse + voff[fd][1]);
      oacc[fd] = __builtin_amdgcn_mfma_f32_16x16x32_bf16(pa0, vf0, oacc[fd], 0, 0, 0);
      oacc[fd] = __builtin_amdgcn_mfma_f32_16x16x32_bf16(pa1, vf1, oacc[fd], 0, 0, 0);
    }
    if (t + 2 < nt) waitv<4>(); else waitv<0>();
    barrier_sb();
    cb = (cb == 2 * KB) ? 0 : (cb + KB);
  }
  #pragma unroll
  for (int fd = 0; fd < 4; fd++)
    #pragma unroll
    for (int r = 0; r < 4; r++){
      int row = b * Ss + iq * 64 + wid * 16 + lc * 4 + r;
      o[(size_t)row * Dd + h * DHh + fd * 16 + lr] = f2bf(oacc[fd][r] / lsum[r]);
    }
}

// ---------------- host ----------------
extern "C" void kernel_launch(void* const* d_in, const int* in_sizes, int n_in,
                              void* d_out, int out_size, void* d_ws, size_t ws_size,
                              hipStream_t stream){
  const int*   ids  = (const int*)d_in[0];
  const float* tok  = (const float*)d_in[1];
  const float* pos  = (const float*)d_in[2];
  const float* Wq   = (const float*)d_in[3];
  const float* bq   = (const float*)d_in[4];
  const float* Wk   = (const float*)d_in[5];
  const float* bk   = (const float*)d_in[6];
  const float* Wv   = (const float*)d_in[7];
  const float* bv   = (const float*)d_in[8];
  const float* Wo   = (const float*)d_in[9];
  const float* bo   = (const float*)d_in[10];
  const float* ln1g = (const float*)d_in[11];
  const float* ln1b = (const float*)d_in[12];
  const float* ln2g = (const float*)d_in[13];
  const float* ln2b = (const float*)d_in[14];
  const float* W1   = (const float*)d_in[15];
  const float* b1   = (const float*)d_in[16];
  const float* W2   = (const float*)d_in[17];
  const float* b2   = (const float*)d_in[18];
  const float* lnfg = (const float*)d_in[19];
  const float* lnfb = (const float*)d_in[20];
  const float* Wh   = (const float*)d_in[21];
  float* out = (float*)d_out;

  auto al = [](size_t x){ return (x + 255) & ~(size_t)255; };
  size_t off = 0;
  auto take = [&](size_t bytes){ size_t r = off; off = al(off + bytes); return r; };
  size_t o_x    = take((size_t)Mtok * Dd * 4);
  size_t o_h    = take((size_t)Mtok * Dd * 2);
  size_t o_qkv  = take((size_t)Mtok * NQKV * 2);
  size_t o_vt   = take((size_t)Bbatch * Hh * DHh * Ss * 2);
  size_t o_o    = take((size_t)Mtok * Dd * 2);
  size_t o_mid  = take((size_t)Mtok * Ff * 2);
  size_t o_bq   = take((size_t)Ll * NQKV * 4);
  size_t o_part = take((size_t)4 * Mtok * Dd * 4);
  size_t o_rot = off;
  size_t o_wqkv, o_wo, o_w1, o_w2, o_wh;
  bool full;
  {
    size_t t = off;
    o_wqkv = t; t = al(t + (size_t)Ll * NQKV * Dd * 2);
    o_wo   = t; t = al(t + (size_t)Ll * Dd * Dd * 2);
    o_w1   = t; t = al(t + (size_t)Ll * Ff * Dd * 2);
    o_w2   = t; t = al(t + (size_t)Ll * Dd * Ff * 2);
    o_wh   = t; t = al(t + (size_t)VPAD * Dd * 2);
    full = (t <= ws_size);
  }
  char* ws = (char*)d_ws;
  float* x    = (float*)(ws + o_x);
  u16*   h    = (u16*)(ws + o_h);
  u16*   qkvb = (u16*)(ws + o_qkv);
  u16*   vtb  = (u16*)(ws + o_vt);
  u16*   ob   = (u16*)(ws + o_o);
  u16*   midb = (u16*)(ws + o_mid);
  float* bqkvp= (float*)(ws + o_bq);
  float* part = (float*)(ws + o_part);
  u16* wqkvT = full ? (u16*)(ws + o_wqkv) : (u16*)(ws + o_rot);
  u16* woT   = full ? (u16*)(ws + o_wo)   : (u16*)(ws + o_rot);
  u16* w1T   = full ? (u16*)(ws + o_w1)   : (u16*)(ws + o_rot);
  u16* w2T   = full ? (u16*)(ws + o_w2)   : (u16*)(ws + o_rot);
  u16* whT   = full ? (u16*)(ws + o_wh)   : (u16*)(ws + o_rot);

  auto tpose = [&](const float* src, u16* dst, int R, int C, int nmat, long smat, long dmat){
    k_transpose<<<dim3((C + 31) / 32, R / 64, nmat), 256, 0, stream>>>(src, dst, R, C, smat, dmat);
  };

  k_biaspack<<<(Ll * NQKV) / 256, 256, 0, stream>>>(bq, bk, bv, bqkvp);
  k_embed<<<Mtok, 256, 0, stream>>>(ids, tok, pos, x);

  if (full){
    tpose(Wq, wqkvT,              Dd, Dd, Ll, (long)Dd * Dd, (long)NQKV * Dd);
    tpose(Wk, wqkvT + Dd * Dd,    Dd, Dd, Ll, (long)Dd * Dd, (long)NQKV * Dd);
    tpose(Wv, wqkvT + 2 * Dd * Dd,Dd, Dd, Ll, (long)Dd * Dd, (long)NQKV * Dd);
    tpose(Wo, woT, Dd, Dd, Ll, (long)Dd * Dd, (long)Dd * Dd);
    tpose(W1, w1T, Dd, Ff, Ll, (long)Dd * Ff, (long)Ff * Dd);
    tpose(W2, w2T, Ff, Dd, Ll, (long)Ff * Dd, (long)Dd * Ff);
    tpose(Wh, whT, Dd, Vv, 1, 0, 0);
  }

  // all grids 1D, nwg % 8 == 0
  auto gemm_qkv = [&](const u16* Aop, const u16* Bop, const float* bias, u16* Cb){
    constexpr int MT = Mtok / 64, NT = NQKV / 128;           // 576
    k_gemm3<64, 128, Dd, 1><<<MT * NT, 256, 0, stream>>>(Aop, Bop, bias, nullptr, Cb, vtb, NQKV, MT, NT);
  };
  auto gemm_wo = [&](const u16* Aop, const u16* Bop, const float* bias, float* C){
    constexpr int MT = Mtok / 64, NT = Dd / 64;              // 384
    k_gemm3<64, 64, Dd, 3><<<MT * NT, 256, 0, stream>>>(Aop, Bop, bias, C, nullptr, nullptr, Dd, MT, NT);
  };
  auto gemm_ffn1 = [&](const u16* Aop, const u16* Bop, const float* bias, u16* Cb){
    constexpr int MT = Mtok / 64, NT = Ff / 128;             // 768
    k_gemm3<64, 128, Dd, 2><<<MT * NT, 256, 0, stream>>>(Aop, Bop, bias, nullptr, Cb, nullptr, Ff, MT, NT);
  };
  auto gemm_ffn2 = [&](const u16* Aop, const u16* Bop){
    constexpr int MT = Mtok / 128, NT = Dd / 128;            // 16 x 6 x 4 = 384
    k_gemm3<128, 128, Ff, 4><<<MT * NT * 4, 256, 0, stream>>>(Aop, Bop, nullptr, part, nullptr, nullptr, Dd, MT, NT);
  };
  auto gemm_head = [&](const u16* Aop, const u16* Bop, float* C){
    constexpr int MT = Mtok / 128, NT = VPAD / 128;          // 6288
    k_gemm3<128, 128, Dd, 0><<<MT * NT, 256, 0, stream>>>(Aop, Bop, nullptr, C, nullptr, nullptr, Vv, MT, NT);
  };

  for (int l = 0; l < Ll; ++l){
    const u16* wqkvL = full ? wqkvT + (size_t)l * NQKV * Dd : wqkvT;
    const u16* woL   = full ? woT   + (size_t)l * Dd * Dd   : woT;
    const u16* w1L   = full ? w1T   + (size_t)l * Ff * Dd   : w1T;
    const u16* w2L   = full ? w2T   + (size_t)l * Dd * Ff   : w2T;
    if (!full){
      tpose(Wq + (size_t)l * Dd * Dd, wqkvT,              Dd, Dd, 1, 0, 0);
      tpose(Wk + (size_t)l * Dd * Dd, wqkvT + Dd * Dd,    Dd, Dd, 1, 0, 0);
      tpose(Wv + (size_t)l * Dd * Dd, wqkvT + 2 * Dd * Dd,Dd, Dd, 1, 0, 0);
    }
    k_ln<<<Mtok, 256, 0, stream>>>(x, ln1g + l * Dd, ln1b + l * Dd, h);
    gemm_qkv(h, wqkvL, bqkvp + l * NQKV, qkvb);
    k_attn<<<dim3(Ss / 64, Bbatch * Hh), 256, 0, stream>>>(qkvb, vtb, ob);
    if (!full) tpose(Wo + (size_t)l * Dd * Dd, woT, Dd, Dd, 1, 0, 0);
    gemm_wo(ob, woL, bo + l * Dd, x);
    k_ln<<<Mtok, 256, 0, stream>>>(x, ln2g + l * Dd, ln2b + l * Dd, h);
    if (!full) tpose(W1 + (size_t)l * Dd * Ff, w1T, Dd, Ff, 1, 0, 0);
    gemm_ffn1(h, w1L, b1 + l * Ff, midb);
    if (!full) tpose(W2 + (size_t)l * Ff * Dd, w2T, Ff, Dd, 1, 0, 0);
    gemm_ffn2(midb, w2L);
    k_combine<<<(Mtok * Dd / 4) / 256, 256, 0, stream>>>(part, b2 + l * Dd, x);
  }
  k_ln<<<Mtok, 256, 0, stream>>>(x, lnfg, lnfb, h);
  if (!full) tpose(Wh, whT, Dd, Vv, 1, 0, 0);
  gemm_head(h, whT, out);
}

// Round 7
// 2132.933 us; speedup vs baseline: 1.2275x; 1.0819x over previous
//
#include <hip/hip_runtime.h>
#include <hip/hip_bf16.h>
#include <cstdint>
#include <cstddef>

#define DEV __device__ __forceinline__

typedef __attribute__((ext_vector_type(8))) short short8;   // 8 bf16 (4 VGPR)
typedef __attribute__((ext_vector_type(4))) short s16x4;
typedef __attribute__((ext_vector_type(4))) float f32x4;
typedef unsigned short u16;
typedef unsigned int u32;

static constexpr int Vv = 50257;
static constexpr int Dd = 768;
static constexpr int Ll = 12;
static constexpr int Hh = 12;
static constexpr int Ff = 3072;
static constexpr int Ss = 1024;
static constexpr int Bbatch = 2;
static constexpr int DHh = 64;
static constexpr int Mtok = Bbatch * Ss;   // 2048
static constexpr int NQKV = 3 * Dd;        // 2304
static constexpr int VPAD = 50304;         // 50257 padded to 128-multiple

DEV u16 f2bf(float f){ u32 x; __builtin_memcpy(&x, &f, 4); x += 0x7fffu + ((x >> 16) & 1u); return (u16)(x >> 16); }

DEV void gld_lds16(const void* g, void* l){
  __builtin_amdgcn_global_load_lds((const __attribute__((address_space(1))) void*)g,
                                   (__attribute__((address_space(3))) void*)l, 16, 0, 0);
}

// ---------------- fused embedding + LN1(layer0): f32 x out, bf16 h out ----------------
__global__ __launch_bounds__(256) void k_embed_ln(const int* __restrict__ ids, const float* __restrict__ tok,
                                                  const float* __restrict__ pos, const float* __restrict__ g,
                                                  const float* __restrict__ b, float* __restrict__ x,
                                                  u16* __restrict__ h){
  int t = blockIdx.x, tid = threadIdx.x;
  int id = ids[t];
  int s = t & (Ss - 1);
  const float* tr = tok + (size_t)id * Dd;
  const float* pr = pos + (size_t)s * Dd;
  float v0 = tr[tid] + pr[tid], v1 = tr[tid + 256] + pr[tid + 256], v2 = tr[tid + 512] + pr[tid + 512];
  float* xr = x + (size_t)t * Dd;
  xr[tid] = v0; xr[tid + 256] = v1; xr[tid + 512] = v2;
  float sm = v0 + v1 + v2, ss = v0 * v0 + v1 * v1 + v2 * v2;
  for (int o = 1; o < 64; o <<= 1){ sm += __shfl_xor(sm, o, 64); ss += __shfl_xor(ss, o, 64); }
  __shared__ float red[8];
  int w = tid >> 6, l = tid & 63;
  if (l == 0){ red[w] = sm; red[w + 4] = ss; }
  __syncthreads();
  sm = red[0] + red[1] + red[2] + red[3];
  ss = red[4] + red[5] + red[6] + red[7];
  float mu = sm * (1.0f / Dd);
  float var = ss * (1.0f / Dd) - mu * mu;
  float rs = rsqrtf(var + 1e-5f);
  u16* yr = h + (size_t)t * Dd;
  yr[tid]       = f2bf((v0 - mu) * rs * g[tid]       + b[tid]);
  yr[tid + 256] = f2bf((v1 - mu) * rs * g[tid + 256] + b[tid + 256]);
  yr[tid + 512] = f2bf((v2 - mu) * rs * g[tid + 512] + b[tid + 512]);
}

// ---------------- layernorm: f32 in -> bf16 out ----------------
__global__ __launch_bounds__(256) void k_ln(const float* __restrict__ x, const float* __restrict__ g,
                                            const float* __restrict__ b, u16* __restrict__ y){
  int row = blockIdx.x, tid = threadIdx.x;
  const float* xr = x + (size_t)row * Dd;
  float v0 = xr[tid], v1 = xr[tid + 256], v2 = xr[tid + 512];
  float s = v0 + v1 + v2, ss = v0 * v0 + v1 * v1 + v2 * v2;
  for (int o = 1; o < 64; o <<= 1){ s += __shfl_xor(s, o, 64); ss += __shfl_xor(ss, o, 64); }
  __shared__ float red[8];
  int w = tid >> 6, l = tid & 63;
  if (l == 0){ red[w] = s; red[w + 4] = ss; }
  __syncthreads();
  s = red[0] + red[1] + red[2] + red[3];
  ss = red[4] + red[5] + red[6] + red[7];
  float mu = s * (1.0f / Dd);
  float var = ss * (1.0f / Dd) - mu * mu;
  float rs = rsqrtf(var + 1e-5f);
  u16* yr = y + (size_t)row * Dd;
  yr[tid]       = f2bf((v0 - mu) * rs * g[tid]       + b[tid]);
  yr[tid + 256] = f2bf((v1 - mu) * rs * g[tid + 256] + b[tid + 256]);
  yr[tid + 512] = f2bf((v2 - mu) * rs * g[tid + 512] + b[tid + 512]);
}

// ---------------- fused: combine 2 split-K partials + bias + residual -> x, then LN -> h ----------------
__global__ __launch_bounds__(256) void k_combineln(const float* __restrict__ p, const float* __restrict__ bias,
                                                   float* __restrict__ x, const float* __restrict__ g,
                                                   const float* __restrict__ b, u16* __restrict__ h){
  constexpr size_t SL = (size_t)Mtok * Dd;
  int row = blockIdx.x, tid = threadIdx.x;
  float* xr = x + (size_t)row * Dd;
  const float* p0 = p + (size_t)row * Dd;
  const float* p1 = p0 + SL;
  float v0 = xr[tid]       + p0[tid]       + p1[tid]       + bias[tid];
  float v1 = xr[tid + 256] + p0[tid + 256] + p1[tid + 256] + bias[tid + 256];
  float v2 = xr[tid + 512] + p0[tid + 512] + p1[tid + 512] + bias[tid + 512];
  xr[tid] = v0; xr[tid + 256] = v1; xr[tid + 512] = v2;
  float s = v0 + v1 + v2, ss = v0 * v0 + v1 * v1 + v2 * v2;
  for (int o = 1; o < 64; o <<= 1){ s += __shfl_xor(s, o, 64); ss += __shfl_xor(ss, o, 64); }
  __shared__ float red[8];
  int w = tid >> 6, l = tid & 63;
  if (l == 0){ red[w] = s; red[w + 4] = ss; }
  __syncthreads();
  s = red[0] + red[1] + red[2] + red[3];
  ss = red[4] + red[5] + red[6] + red[7];
  float mu = s * (1.0f / Dd);
  float var = ss * (1.0f / Dd) - mu * mu;
  float rs = rsqrtf(var + 1e-5f);
  u16* yr = h + (size_t)row * Dd;
  yr[tid]       = f2bf((v0 - mu) * rs * g[tid]       + b[tid]);
  yr[tid + 256] = f2bf((v1 - mu) * rs * g[tid + 256] + b[tid + 256]);
  yr[tid + 512] = f2bf((v2 - mu) * rs * g[tid + 512] + b[tid + 512]);
}

// ---------------- transpose+convert: f32 [R][C] -> bf16 [C][R], 64r x 32c tiles ----------------
__global__ __launch_bounds__(256) void k_transpose(const float* __restrict__ src, u16* __restrict__ dst,
                                                   int R, int C, long smat, long dmat){
  __shared__ float tile[64][33];
  src += (size_t)blockIdx.z * smat;
  dst += (size_t)blockIdx.z * dmat;
  int c0 = blockIdx.x * 32, r0 = blockIdx.y * 64;
  int tid = threadIdx.x;
  int tc = tid & 31, tr = tid >> 5;
  #pragma unroll
  for (int i = 0; i < 8; i++){
    int r = tr + i * 8, c = c0 + tc;
    tile[r][tc] = (c < C) ? src[(size_t)(r0 + r) * C + c] : 0.0f;
  }
  __syncthreads();
  #pragma unroll
  for (int it = 0; it < 2; it++){
    int id = it * 256 + tid;
    int c = id & 31, rg = id >> 5, r = rg * 4;
    int cc = c0 + c;
    if (cc < C){
      s16x4 v = { (short)f2bf(tile[r][c]), (short)f2bf(tile[r + 1][c]),
                  (short)f2bf(tile[r + 2][c]), (short)f2bf(tile[r + 3][c]) };
      *(s16x4*)(dst + (size_t)cc * R + r0 + r) = v;
    }
  }
}

// ---------------- pack [bq;bk;bv] per layer into [L][2304] ----------------
__global__ void k_biaspack(const float* __restrict__ bq, const float* __restrict__ bk,
                           const float* __restrict__ bv, float* __restrict__ o){
  int i = blockIdx.x * 256 + threadIdx.x;
  int col = i % NQKV, lay = i / NQKV;
  float v = (col < Dd) ? bq[lay * Dd + col]
          : (col < 2 * Dd) ? bk[lay * Dd + col - Dd]
          : bv[lay * Dd + col - 2 * Dd];
  o[i] = v;
}

// ---------------- 2-phase double-buffered GEMM (round-2 structure, vectorized epilogues) ----------------
// C[M=2048, N] = A * Bt^T (bf16, Bt is [N][K-stride]).
// EPI: 0 head (f32, original orientation col=lane&15, scalar stores, N-bounded)
//      1 qkv (swapped; bf16+bias+qscale; fused V-transpose, V-cols only to vt)
//      2 ffn1 (swapped; bf16+bias+GELU)
//      3 wo (swapped; f32 +bias+residual in-place)
//      4 ffn2 split-K=2 partial (swapped; f32)
template<int BM, int BN, int EPI>
__global__ __launch_bounds__(256) void k_gemmF(const u16* __restrict__ A, const u16* __restrict__ Bt,
    const float* __restrict__ bias, float* __restrict__ Cf, u16* __restrict__ Cb,
    u16* __restrict__ vt, int Nn, int MT, int NT){
  constexpr bool SPLIT = (EPI == 4);
  constexpr int KST  = SPLIT ? Ff : Dd;
  constexpr int KLEN = SPLIT ? (Ff / 2) : Dd;
  constexpr int nk = KLEN / 32;
  constexpr int HM = BM / 2, HN = BN / 2, FM = HM / 16, FN = HN / 16;
  constexpr int nA = (BM * 4) / 256, nB = (BN * 4) / 256;
  constexpr int ABYTE = BM * 64, BBYTE = BN * 64;     // bytes per buffer
  __shared__ __align__(16) u16 ldsA[2 * BM * 32];
  __shared__ __align__(16) u16 ldsB[2 * BN * 32];
  int tid = threadIdx.x, wid = tid >> 6, l = tid & 63;
  int wm = wid >> 1, wn = wid & 1;
  int lr = l & 15, lc = l >> 4;
  int nwg = gridDim.x, dIdx = blockIdx.x;
  int L = (dIdx & 7) * (nwg >> 3) + (dIdx >> 3);      // XCD-chunked, nwg % 8 == 0
  int kidx = 0;
  if (SPLIT){ int per = MT * NT; kidx = L / per; L -= kidx * per; }
  int mtile = L % MT, ntile = L / MT;
  int m0 = mtile * BM, n0 = ntile * BN;
  int kbase = kidx * KLEN;

  const u16* gA[nA]; u16* dA[nA];
  const u16* gB[nB]; u16* dB[nB];
  #pragma unroll
  for (int i = 0; i < nA; i++){
    int id = i * 256 + tid, row = id >> 2, c = id & 3;
    int cs = c ^ ((row >> 1) & 3);
    gA[i] = A + (size_t)(m0 + row) * KST + kbase + cs * 8;
    dA[i] = ldsA + id * 8;
  }
  #pragma unroll
  for (int i = 0; i < nB; i++){
    int id = i * 256 + tid, row = id >> 2, c = id & 3;
    int cs = c ^ ((row >> 1) & 3);
    gB[i] = Bt + (size_t)(n0 + row) * KST + kbase + cs * 8;
    dB[i] = ldsB + id * 8;
  }
  int offA[FM], offB[FN];
  #pragma unroll
  for (int i = 0; i < FM; i++){
    int row = wm * HM + i * 16 + lr;
    offA[i] = row * 64 + ((lc ^ ((row >> 1) & 3)) << 4);
  }
  #pragma unroll
  for (int j = 0; j < FN; j++){
    int row = wn * HN + j * 16 + lr;
    offB[j] = row * 64 + ((lc ^ ((row >> 1) & 3)) << 4);
  }

  f32x4 acc[FM][FN];
  #pragma unroll
  for (int i = 0; i < FM; i++)
    #pragma unroll
    for (int j = 0; j < FN; j++) acc[i][j] = (f32x4)0.0f;

  auto stage = [&](int buf){
    #pragma unroll
    for (int i = 0; i < nA; i++){ gld_lds16(gA[i], (char*)dA[i] + buf * ABYTE); gA[i] += 32; }
    #pragma unroll
    for (int i = 0; i < nB; i++){ gld_lds16(gB[i], (char*)dB[i] + buf * BBYTE); gB[i] += 32; }
  };
  auto compute = [&](int buf){
    const char* bA = (const char*)ldsA + buf * ABYTE;
    const char* bB = (const char*)ldsB + buf * BBYTE;
    short8 af[FM], bfr[FN];
    #pragma unroll
    for (int i = 0; i < FM; i++) af[i] = *(const short8*)(bA + offA[i]);
    #pragma unroll
    for (int j = 0; j < FN; j++) bfr[j] = *(const short8*)(bB + offB[j]);
    #pragma unroll
    for (int i = 0; i < FM; i++)
      #pragma unroll
      for (int j = 0; j < FN; j++){
        if (EPI == 0)
          acc[i][j] = __builtin_amdgcn_mfma_f32_16x16x32_bf16(af[i], bfr[j], acc[i][j], 0, 0, 0);
        else  // swapped: lane holds one row, 4 consecutive cols
          acc[i][j] = __builtin_amdgcn_mfma_f32_16x16x32_bf16(bfr[j], af[i], acc[i][j], 0, 0, 0);
      }
  };

  stage(0);
  __syncthreads();
  #pragma unroll 1
  for (int t = 0; t < nk - 1; ++t){
    stage((t + 1) & 1);
    compute(t & 1);
    __syncthreads();
  }
  compute((nk - 1) & 1);

  if (EPI == 0){
    #pragma unroll
    for (int i = 0; i < FM; i++){
      #pragma unroll
      for (int j = 0; j < FN; j++){
        int col = n0 + wn * HN + j * 16 + lr;
        if (col >= Nn) continue;
        #pragma unroll
        for (int r = 0; r < 4; r++){
          int row = m0 + wm * HM + i * 16 + lc * 4 + r;
          Cf[(size_t)row * Nn + col] = acc[i][j][r];
        }
      }
    }
    return;
  }
  // swapped orientation: row = ..+lr, cols c0..c0+3
  #pragma unroll
  for (int i = 0; i < FM; i++){
    int row = m0 + wm * HM + i * 16 + lr;
    #pragma unroll
    for (int j = 0; j < FN; j++){
      int c0 = n0 + wn * HN + j * 16 + lc * 4;
      f32x4 v = acc[i][j];
      if (EPI == 4){
        *(f32x4*)(Cf + (size_t)kidx * Mtok * Dd + (size_t)row * Dd + c0) = v;
        continue;
      }
      f32x4 bv = *(const f32x4*)(bias + c0);
      v = v + bv;
      if (EPI == 3){
        f32x4* p = (f32x4*)(Cf + (size_t)row * Nn + c0);
        *p = *p + v;
        continue;
      }
      if (EPI == 1 && c0 < Dd) v = v * 0.125f;
      if (EPI == 2){
        #pragma unroll
        for (int r = 0; r < 4; r++) v[r] = 0.5f * v[r] * (1.0f + erff(v[r] * 0.70710678118f));
      }
      u16 q0 = f2bf(v[0]), q1 = f2bf(v[1]), q2 = f2bf(v[2]), q3 = f2bf(v[3]);
      if (EPI == 1 && c0 >= 2 * Dd){
        // V columns -> vt[bh][d][s] only (attn reads V from vt)
        int c2 = c0 - 2 * Dd, hh = c2 >> 6, dd2 = c2 & 63;
        int bb = row >> 10, ss2 = row & 1023;
        size_t base = ((size_t)((bb * Hh + hh) * DHh + dd2)) << 10;
        vt[base + ss2] = q0;
        vt[base + (1 << 10) + ss2] = q1;
        vt[base + (2 << 10) + ss2] = q2;
        vt[base + (3 << 10) + ss2] = q3;
      } else {
        s16x4 pv = { (short)q0, (short)q1, (short)q2, (short)q3 };
        *(s16x4*)(Cb + (size_t)row * Nn + c0) = pv;
      }
    }
  }
}

// ---------------- flash-style causal attention (swapped QK^T and PV, scalar softmax state) ----------------
// 1D grid 384 = (S/64) x (B*H), longest iq first. 4 waves; wave owns 16 q rows (q = wid*16 + lane&15).
__global__ __launch_bounds__(256) void k_attn(const u16* __restrict__ qkv, const u16* __restrict__ vt,
                                              u16* __restrict__ o){
  __shared__ __align__(16) u16 ldsK[64 * 64];
  __shared__ __align__(16) u16 ldsV[64 * 64];
  __shared__ __align__(16) u16 ldsP[4][16 * 72];   // per-wave P[q][k], row stride 72 u16
  int bid = blockIdx.x;
  int iq = (Ss / 64) - 1 - (bid / (Bbatch * Hh));  // longest first
  int bh = bid % (Bbatch * Hh);
  int b = bh / Hh, h = bh % Hh;
  int tid = threadIdx.x, wid = tid >> 6, l = tid & 63, lr = l & 15, lc = l >> 4;
  int nt = iq + 1;
  int qrow = b * Ss + iq * 64 + wid * 16 + lr;
  const u16* qp = qkv + (size_t)qrow * NQKV + h * DHh;
  short8 qf0 = *(const short8*)(qp + lc * 8);
  short8 qf1 = *(const short8*)(qp + 32 + lc * 8);

  const u16* gK[2]; const u16* gV[2]; u16* dK[2]; u16* dV[2];
  #pragma unroll
  for (int c = 0; c < 2; c++){
    int id = c * 256 + tid, row = id >> 3, ch = id & 7;
    int cs = ch ^ (row & 7);
    gK[c] = qkv + (size_t)(b * Ss + row) * NQKV + Dd + h * DHh + cs * 8;
    gV[c] = vt + ((size_t)(bh * DHh) + row) * Ss + cs * 8;
    dK[c] = ldsK + id * 8;
    dV[c] = ldsV + id * 8;
  }
  int koff[4][2];
  #pragma unroll
  for (int fn = 0; fn < 4; fn++){
    int kv = fn * 16 + lr;
    #pragma unroll
    for (int ks = 0; ks < 2; ks++){
      int ch = ks * 4 + lc;
      koff[fn][ks] = kv * 128 + ((ch ^ (kv & 7)) << 4);
    }
  }

  float mreg = -1e30f, lsum = 0.0f;
  f32x4 oacc[4];
  #pragma unroll
  for (int i = 0; i < 4; i++) oacc[i] = (f32x4)0.0f;
  u16* pbase = ldsP[wid];

  #pragma unroll 1
  for (int t = 0; t < nt; ++t){
    #pragma unroll
    for (int c = 0; c < 2; c++){ gld_lds16(gK[c], dK[c]); gK[c] += (size_t)64 * NQKV; }
    #pragma unroll
    for (int c = 0; c < 2; c++){ gld_lds16(gV[c], dV[c]); gV[c] += 64; }
    __syncthreads();
    f32x4 sc[4];
    __builtin_amdgcn_s_setprio(1);
    #pragma unroll
    for (int fn = 0; fn < 4; fn++){
      short8 kf0 = *(const short8*)((const char*)ldsK + koff[fn][0]);
      short8 kf1 = *(const short8*)((const char*)ldsK + koff[fn][1]);
      sc[fn] = __builtin_amdgcn_mfma_f32_16x16x32_bf16(kf0, qf0, (f32x4)0.0f, 0, 0, 0);
      sc[fn] = __builtin_amdgcn_mfma_f32_16x16x32_bf16(kf1, qf1, sc[fn], 0, 0, 0);
    }
    __builtin_amdgcn_s_setprio(0);
    // lane holds S[k = fn*16 + lc*4 + r][q = wid*16 + lr]
    if (t == iq){
      #pragma unroll
      for (int fn = 0; fn < 4; fn++)
        #pragma unroll
        for (int r = 0; r < 4; r++)
          if (fn * 16 + lc * 4 + r > wid * 16 + lr) sc[fn][r] = -1e30f;
    }
    float pm = sc[0][0];
    #pragma unroll
    for (int fn = 0; fn < 4; fn++)
      #pragma unroll
      for (int r = 0; r < 4; r++) pm = fmaxf(pm, sc[fn][r]);
    pm = fmaxf(pm, __shfl_xor(pm, 16, 64));
    pm = fmaxf(pm, __shfl_xor(pm, 32, 64));
    float mnew = fmaxf(mreg, pm);
    float alpha = __expf(mreg - mnew);
    mreg = mnew;
    float rs = 0.0f;
    #pragma unroll
    for (int fn = 0; fn < 4; fn++)
      #pragma unroll
      for (int r = 0; r < 4; r++){
        float p = __expf(sc[fn][r] - mnew);
        sc[fn][r] = p;
        rs += p;
      }
    rs += __shfl_xor(rs, 16, 64);
    rs += __shfl_xor(rs, 32, 64);
    lsum = lsum * alpha + rs;
    // P write: row q=lr, k = fn*16 + lc*4 + r  (4 consecutive -> s16x4)
    #pragma unroll
    for (int fn = 0; fn < 4; fn++){
      s16x4 pv = { (short)f2bf(sc[fn][0]), (short)f2bf(sc[fn][1]),
                   (short)f2bf(sc[fn][2]), (short)f2bf(sc[fn][3]) };
      *(s16x4*)((char*)pbase + lr * 144 + fn * 32 + lc * 8) = pv;
    }
    asm volatile("s_waitcnt lgkmcnt(0)" ::: "memory");
    __builtin_amdgcn_sched_barrier(0);
    #pragma unroll
    for (int fd = 0; fd < 4; fd++)
      #pragma unroll
      for (int r = 0; r < 4; r++) oacc[fd][r] *= alpha;
    short8 pa0 = *(const short8*)((const char*)pbase + lr * 144 + lc * 16);
    short8 pa1 = *(const short8*)((const char*)pbase + lr * 144 + 64 + lc * 16);
    __builtin_amdgcn_s_setprio(1);
    #pragma unroll
    for (int fd = 0; fd < 4; fd++){
      short8 vf0 = *(const short8*)((const char*)ldsV + koff[fd][0]);
      short8 vf1 = *(const short8*)((const char*)ldsV + koff[fd][1]);
      oacc[fd] = __builtin_amdgcn_mfma_f32_16x16x32_bf16(vf0, pa0, oacc[fd], 0, 0, 0);
      oacc[fd] = __builtin_amdgcn_mfma_f32_16x16x32_bf16(vf1, pa1, oacc[fd], 0, 0, 0);
    }
    __builtin_amdgcn_s_setprio(0);
    __syncthreads();
  }
  // oacc[fd][r] = O[q = wid*16+lr][d = fd*16 + lc*4 + r]
  float inv = 1.0f / lsum;
  int rowg = b * Ss + iq * 64 + wid * 16 + lr;
  #pragma unroll
  for (int fd = 0; fd < 4; fd++){
    s16x4 ov = { (short)f2bf(oacc[fd][0] * inv), (short)f2bf(oacc[fd][1] * inv),
                 (short)f2bf(oacc[fd][2] * inv), (short)f2bf(oacc[fd][3] * inv) };
    *(s16x4*)(o + (size_t)rowg * Dd + h * DHh + fd * 16 + lc * 4) = ov;
  }
}

// ---------------- host ----------------
extern "C" void kernel_launch(void* const* d_in, const int* in_sizes, int n_in,
                              void* d_out, int out_size, void* d_ws, size_t ws_size,
                              hipStream_t stream){
  const int*   ids  = (const int*)d_in[0];
  const float* tok  = (const float*)d_in[1];
  const float* pos  = (const float*)d_in[2];
  const float* Wq   = (const float*)d_in[3];
  const float* bq   = (const float*)d_in[4];
  const float* Wk   = (const float*)d_in[5];
  const float* bk   = (const float*)d_in[6];
  const float* Wv   = (const float*)d_in[7];
  const float* bv   = (const float*)d_in[8];
  const float* Wo   = (const float*)d_in[9];
  const float* bo   = (const float*)d_in[10];
  const float* ln1g = (const float*)d_in[11];
  const float* ln1b = (const float*)d_in[12];
  const float* ln2g = (const float*)d_in[13];
  const float* ln2b = (const float*)d_in[14];
  const float* W1   = (const float*)d_in[15];
  const float* b1   = (const float*)d_in[16];
  const float* W2   = (const float*)d_in[17];
  const float* b2   = (const float*)d_in[18];
  const float* lnfg = (const float*)d_in[19];
  const float* lnfb = (const float*)d_in[20];
  const float* Wh   = (const float*)d_in[21];
  float* out = (float*)d_out;

  auto al = [](size_t x){ return (x + 255) & ~(size_t)255; };
  size_t off = 0;
  auto take = [&](size_t bytes){ size_t r = off; off = al(off + bytes); return r; };
  size_t o_x    = take((size_t)Mtok * Dd * 4);
  size_t o_h    = take((size_t)Mtok * Dd * 2);
  size_t o_qkv  = take((size_t)Mtok * NQKV * 2);
  size_t o_vt   = take((size_t)Bbatch * Hh * DHh * Ss * 2);
  size_t o_o    = take((size_t)Mtok * Dd * 2);
  size_t o_mid  = take((size_t)Mtok * Ff * 2);
  size_t o_bq   = take((size_t)Ll * NQKV * 4);
  size_t o_part = take((size_t)2 * Mtok * Dd * 4);
  size_t o_rot = off;
  size_t o_wqkv, o_wo, o_w1, o_w2, o_wh;
  bool full;
  {
    size_t t = off;
    o_wqkv = t; t = al(t + (size_t)Ll * NQKV * Dd * 2);
    o_wo   = t; t = al(t + (size_t)Ll * Dd * Dd * 2);
    o_w1   = t; t = al(t + (size_t)Ll * Ff * Dd * 2);
    o_w2   = t; t = al(t + (size_t)Ll * Dd * Ff * 2);
    o_wh   = t; t = al(t + (size_t)VPAD * Dd * 2);
    full = (t <= ws_size);
  }
  char* ws = (char*)d_ws;
  float* x    = (float*)(ws + o_x);
  u16*   h    = (u16*)(ws + o_h);
  u16*   qkvb = (u16*)(ws + o_qkv);
  u16*   vtb  = (u16*)(ws + o_vt);
  u16*   ob   = (u16*)(ws + o_o);
  u16*   midb = (u16*)(ws + o_mid);
  float* bqkvp= (float*)(ws + o_bq);
  float* part = (float*)(ws + o_part);
  u16* wqkvT = full ? (u16*)(ws + o_wqkv) : (u16*)(ws + o_rot);
  u16* woT   = full ? (u16*)(ws + o_wo)   : (u16*)(ws + o_rot);
  u16* w1T   = full ? (u16*)(ws + o_w1)   : (u16*)(ws + o_rot);
  u16* w2T   = full ? (u16*)(ws + o_w2)   : (u16*)(ws + o_rot);
  u16* whT   = full ? (u16*)(ws + o_wh)   : (u16*)(ws + o_rot);

  auto tpose = [&](const float* src, u16* dst, int R, int C, int nmat, long smat, long dmat){
    k_transpose<<<dim3((C + 31) / 32, R / 64, nmat), 256, 0, stream>>>(src, dst, R, C, smat, dmat);
  };

  k_biaspack<<<(Ll * NQKV) / 256, 256, 0, stream>>>(bq, bk, bv, bqkvp);
  k_embed_ln<<<Mtok, 256, 0, stream>>>(ids, tok, pos, ln1g, ln1b, x, h);

  if (full){
    tpose(Wq, wqkvT,              Dd, Dd, Ll, (long)Dd * Dd, (long)NQKV * Dd);
    tpose(Wk, wqkvT + Dd * Dd,    Dd, Dd, Ll, (long)Dd * Dd, (long)NQKV * Dd);
    tpose(Wv, wqkvT + 2 * Dd * Dd,Dd, Dd, Ll, (long)Dd * Dd, (long)NQKV * Dd);
    tpose(Wo, woT, Dd, Dd, Ll, (long)Dd * Dd, (long)Dd * Dd);
    tpose(W1, w1T, Dd, Ff, Ll, (long)Dd * Ff, (long)Ff * Dd);
    tpose(W2, w2T, Ff, Dd, Ll, (long)Ff * Dd, (long)Dd * Ff);
    tpose(Wh, whT, Dd, Vv, 1, 0, 0);
  }

  // all grids 1D, nwg % 8 == 0
  auto gemm_qkv = [&](const u16* Aop, const u16* Bop, const float* bias, u16* Cb){
    constexpr int MT = Mtok / 64, NT = NQKV / 128;           // 576
    k_gemmF<64, 128, 1><<<MT * NT, 256, 0, stream>>>(Aop, Bop, bias, nullptr, Cb, vtb, NQKV, MT, NT);
  };
  auto gemm_wo = [&](const u16* Aop, const u16* Bop, const float* bias, float* C){
    constexpr int MT = Mtok / 64, NT = Dd / 64;              // 384
    k_gemmF<64, 64, 3><<<MT * NT, 256, 0, stream>>>(Aop, Bop, bias, C, nullptr, nullptr, Dd, MT, NT);
  };
  auto gemm_ffn1 = [&](const u16* Aop, const u16* Bop, const float* bias, u16* Cb){
    constexpr int MT = Mtok / 64, NT = Ff / 128;             // 768
    k_gemmF<64, 128, 2><<<MT * NT, 256, 0, stream>>>(Aop, Bop, bias, nullptr, Cb, nullptr, Ff, MT, NT);
  };
  auto gemm_ffn2 = [&](const u16* Aop, const u16* Bop){
    constexpr int MT = Mtok / 64, NT = Dd / 64;              // 32x12x2 = 768
    k_gemmF<64, 64, 4><<<MT * NT * 2, 256, 0, stream>>>(Aop, Bop, nullptr, part, nullptr, nullptr, Dd, MT, NT);
  };
  auto gemm_head = [&](const u16* Aop, const u16* Bop, float* C){
    constexpr int MT = Mtok / 128, NT = VPAD / 128;          // 6288
    k_gemmF<128, 128, 0><<<MT * NT, 256, 0, stream>>>(Aop, Bop, nullptr, C, nullptr, nullptr, Vv, MT, NT);
  };

  for (int l = 0; l < Ll; ++l){
    const u16* wqkvL = full ? wqkvT + (size_t)l * NQKV * Dd : wqkvT;
    const u16* woL   = full ? woT   + (size_t)l * Dd * Dd   : woT;
    const u16* w1L   = full ? w1T   + (size_t)l * Ff * Dd   : w1T;
    const u16* w2L   = full ? w2T   + (size_t)l * Dd * Ff   : w2T;
    if (!full){
      tpose(Wq + (size_t)l * Dd * Dd, wqkvT,              Dd, Dd, 1, 0, 0);
      tpose(Wk + (size_t)l * Dd * Dd, wqkvT + Dd * Dd,    Dd, Dd, 1, 0, 0);
      tpose(Wv + (size_t)l * Dd * Dd, wqkvT + 2 * Dd * Dd,Dd, Dd, 1, 0, 0);
    }
    gemm_qkv(h, wqkvL, bqkvp + l * NQKV, qkvb);
    k_attn<<<(Ss / 64) * Bbatch * Hh, 256, 0, stream>>>(qkvb, vtb, ob);
    if (!full) tpose(Wo + (size_t)l * Dd * Dd, woT, Dd, Dd, 1, 0, 0);
    gemm_wo(ob, woL, bo + l * Dd, x);
    k_ln<<<Mtok, 256, 0, stream>>>(x, ln2g + l * Dd, ln2b + l * Dd, h);
    if (!full) tpose(W1 + (size_t)l * Dd * Ff, w1T, Dd, Ff, 1, 0, 0);
    gemm_ffn1(h, w1L, b1 + l * Ff, midb);
    if (!full) tpose(W2 + (size_t)l * Ff * Dd, w2T, Ff, Dd, 1, 0, 0);
    gemm_ffn2(midb, w2L);
    const float* gN = (l + 1 < Ll) ? (ln1g + (l + 1) * Dd) : lnfg;
    const float* bN = (l + 1 < Ll) ? (ln1b + (l + 1) * Dd) : lnfb;
    k_combineln<<<Mtok, 256, 0, stream>>>(part, b2 + l * Dd, x, gN, bN, h);
  }
  if (!full) tpose(Wh, whT, Dd, Vv, 1, 0, 0);
  gemm_head(h, whT, out);
}